// Round 11
// baseline (609.464 us; speedup 1.0000x reference)
//
#include <hip/hip_runtime.h>
#include <hip/hip_cooperative_groups.h>
#include <cstdint>
#include <cstddef>

namespace cg = cooperative_groups;

#define N_NODES 4096
#define NWORDS  64          // 4096 bits / 64
#define E_EDGES 131072
#define D_FEAT  256
#define D4      (D_FEAT/4)  // 64 ushort4 groups per row (4 feats per lane)
#define ELL     128         // fixed slots per node (Poisson(32) -> P(deg>128) ~ 1e-40)
#define NBLK    512         // 2 blocks/CU on 256 CUs -> cooperative co-residency guaranteed
#define NTHR    256
#define NTOT    (NBLK * NTHR)   // 131072 threads, 2048 waves

typedef unsigned long long u64;

__device__ inline float bf2f(unsigned short u) {
    return __uint_as_float(((unsigned int)u) << 16);
}
__device__ inline unsigned short f2bf(float f) {   // round-to-nearest-even
    unsigned int u = __float_as_uint(f);
    return (unsigned short)((u + 0x7fffu + ((u >> 16) & 1u)) >> 16);
}

struct Params {
    const int* ei;
    const float* x;
    const float* Ws; const float* bs;
    const float* Wd; const float* bd;
    float* out;
    u64* Ab; u64* Atb;            // bitsets (contiguous with csub_o|csub_i for zeroing)
    float* csub_o; float* csub_i;
    unsigned short* xb;           // bf16 x
    float* d_o; float* d_i;
    int* ideg_o; int* ideg_i;
    int* col_o; int* col_i;       // ELL column lists
    float* ce_o; float* ce_i;     // per-edge common-neighbor counts
    float* rsub_o; float* rsub_i;
    float* s_do; float* s_di;
    float* ro_s; float* co_s; float* ri_s; float* ci_s;
    unsigned short* zbuf; unsigned short* z2buf;   // bf16 intermediates
    float* Ysrc; float* Ydst;
};

// Single cooperative kernel: all 8 phases with grid-wide syncs.
__global__ __launch_bounds__(NTHR, 2) void k_all(Params P) {
    cg::grid_group grid = cg::this_grid();
    __shared__ float smem[32 * 68 + 32 * 36];   // P7: As|Bs ; P2: per-wave lcol slices
    const int tid   = threadIdx.x;
    const int gid   = blockIdx.x * NTHR + tid;
    const int lane  = tid & 63;
    const int wslot = tid >> 6;                 // wave within block (0..3)
    const int gwave = gid >> 6;                 // 0..2047

    // ================= P0: zero bitsets+csub; x -> bf16 =================
    {
        // Ab|Atb|csub_o|csub_i are contiguous: (2*4096*64) u64 + 8192 floats
        u64* zp = P.Ab;
        const int nz = 2 * N_NODES * NWORDS + (2 * N_NODES) / 2;   // 528384 u64
        for (int i = gid; i < nz; i += NTOT) zp[i] = 0ull;
        const float4* x4 = (const float4*)P.x;
        ushort4* xb4 = (ushort4*)P.xb;
        for (int i = gid; i < N_NODES * D_FEAT / 4; i += NTOT) {
            float4 v = x4[i];
            ushort4 q = { f2bf(v.x), f2bf(v.y), f2bf(v.z), f2bf(v.w) };
            xb4[i] = q;
        }
    }
    grid.sync();

    // ================= P1: scatter edges into bitsets =================
    for (int e = gid; e < E_EDGES; e += NTOT) {
        int r = P.ei[e];
        int c = P.ei[E_EDGES + e];
        atomicOr(&P.Ab [(size_t)r * NWORDS + (c >> 6)], 1ull << (c & 63));
        atomicOr(&P.Atb[(size_t)c * NWORDS + (r >> 6)], 1ull << (r & 63));
    }
    grid.sync();

    // ================= P2: ELL fill + degree + per-edge intersections =================
    {
        int* lcol = (int*)smem + wslot * ELL;
        for (int nd = gwave; nd < 2 * N_NODES; nd += 2048) {
            int half = nd >= N_NODES;
            int wid  = half ? nd - N_NODES : nd;
            const u64* bits = half ? P.Atb : P.Ab;
            int*       cols = half ? P.col_i : P.col_o;
            float*     dd   = half ? P.d_i   : P.d_o;
            int*       idg  = half ? P.ideg_i : P.ideg_o;
            float*     ce   = half ? P.ce_i   : P.ce_o;
            float*     rsub = half ? P.rsub_i : P.rsub_o;
            float*     csub = half ? P.csub_i : P.csub_o;
            // --- extract list ---
            u64 wv = bits[(size_t)wid * NWORDS + lane];
            int cnt = __popcll(wv);
            int inc = cnt;
            for (int off = 1; off < 64; off <<= 1) {
                int t = __shfl_up(inc, off);
                if (lane >= off) inc += t;
            }
            int deg = __shfl(inc, 63);
            int pos = inc - cnt;
            u64 t = wv;
            int base = wid << 7;
            while (t) {
                int b = __builtin_ctzll(t);
                int c = lane * 64 + b;
                lcol[pos] = c;
                cols[base + pos] = c;
                ++pos;
                t &= t - 1;
            }
            if (lane == 63) { dd[wid] = (float)deg; idg[wid] = deg; }
            // --- intersections: 16-lane groups, 4 edges in flight ---
            int g = lane >> 4, s = lane & 15;
            const u64* aw = &bits[(size_t)wid * NWORDS + s * 4];
            u64 a0 = aw[0], a1 = aw[1], a2 = aw[2], a3 = aw[3];
            float rs = 0.f;
            for (int p = g; p < deg; p += 4) {
                int j = lcol[p];
                const u64* bw = &bits[(size_t)j * NWORDS + s * 4];
                u64 b0 = bw[0], b1 = bw[1], b2 = bw[2], b3 = bw[3];
                int c = __popcll(a0 & b0) + __popcll(a1 & b1) + __popcll(a2 & b2) + __popcll(a3 & b3);
                c += __shfl_xor(c, 1);
                c += __shfl_xor(c, 2);
                c += __shfl_xor(c, 4);
                c += __shfl_xor(c, 8);
                if (s == 0) {
                    float cf = (j == wid) ? 0.f : (float)c;
                    ce[base + p] = cf;
                    if (cf != 0.f) atomicAdd(&csub[j], cf);
                    rs += cf;
                }
            }
            rs += __shfl_xor(rs, 16); rs += __shfl_xor(rs, 32);
            if (lane == 0) rsub[wid] = rs;
        }
    }
    grid.sync();

    // ================= P3: rfull gather + scales =================
    for (int nd = gwave; nd < 2 * N_NODES; nd += 2048) {
        int half = nd >= N_NODES;
        int wid  = half ? nd - N_NODES : nd;
        const int*   cols = half ? P.col_i  : P.col_o;
        const int*   idg  = half ? P.ideg_i : P.ideg_o;
        const float* dcol = half ? P.d_o    : P.d_i;    // neighbor degree, other direction
        int deg = idg[wid];
        int base = wid << 7;
        float rf = 0.f;
        for (int l = lane; l < deg; l += 64) rf += dcol[cols[base + l]];
        for (int off = 32; off; off >>= 1) rf += __shfl_xor(rf, off);
        if (lane == 0) {
            float dself = (half ? P.d_i : P.d_o)[wid];
            float sd = dself > 0.f ? rsqrtf(dself) : 0.f;
            (half ? P.s_di : P.s_do)[wid] = sd;
            float rsv = (half ? P.rsub_i : P.rsub_o)[wid];
            float csv = (half ? P.csub_i : P.csub_o)[wid];
            float r_ = rf - dself - rsv;
            float c_ = rf - dself - csv;
            (half ? P.ri_s : P.ro_s)[wid] = r_ > 0.f ? rsqrtf(r_) : 0.f;
            (half ? P.ci_s : P.co_s)[wid] = c_ > 0.f ? rsqrtf(c_) : 0.f;
        }
    }
    grid.sync();

    // ================= P4: pass A (csr_in) -> Ydst partial + z =================
    {
        const ushort4* x4 = (const ushort4*)P.xb;
        for (int wid = gwave; wid < N_NODES; wid += 2048) {
            float4 a1 = {0,0,0,0}, a2 = {0,0,0,0}, az = {0,0,0,0};
            int p0 = wid << 7, p1 = p0 + P.ideg_i[wid];
            int p = p0;
            for (; p + 4 <= p1; p += 4) {
                int j0 = P.col_i[p], j1 = P.col_i[p+1], j2 = P.col_i[p+2], j3 = P.col_i[p+3];
                ushort4 q0 = x4[(size_t)j0 * D4 + lane];
                ushort4 q1 = x4[(size_t)j1 * D4 + lane];
                ushort4 q2 = x4[(size_t)j2 * D4 + lane];
                ushort4 q3 = x4[(size_t)j3 * D4 + lane];
                float f0 = P.s_do[j0], f1 = P.s_do[j1], f2 = P.s_do[j2], f3 = P.s_do[j3];
                float s0 = P.ce_i[p]   * P.ci_s[j0];
                float s1 = P.ce_i[p+1] * P.ci_s[j1];
                float s2 = P.ce_i[p+2] * P.ci_s[j2];
                float s3 = P.ce_i[p+3] * P.ci_s[j3];
                float z0 = P.co_s[j0], z1 = P.co_s[j1], z2 = P.co_s[j2], z3 = P.co_s[j3];
                float v0x = bf2f(q0.x), v0y = bf2f(q0.y), v0z = bf2f(q0.z), v0w = bf2f(q0.w);
                float v1x = bf2f(q1.x), v1y = bf2f(q1.y), v1z = bf2f(q1.z), v1w = bf2f(q1.w);
                float v2x = bf2f(q2.x), v2y = bf2f(q2.y), v2z = bf2f(q2.z), v2w = bf2f(q2.w);
                float v3x = bf2f(q3.x), v3y = bf2f(q3.y), v3z = bf2f(q3.z), v3w = bf2f(q3.w);
                a1.x += f0*v0x + f1*v1x + f2*v2x + f3*v3x;
                a1.y += f0*v0y + f1*v1y + f2*v2y + f3*v3y;
                a1.z += f0*v0z + f1*v1z + f2*v2z + f3*v3z;
                a1.w += f0*v0w + f1*v1w + f2*v2w + f3*v3w;
                a2.x += s0*v0x + s1*v1x + s2*v2x + s3*v3x;
                a2.y += s0*v0y + s1*v1y + s2*v2y + s3*v3y;
                a2.z += s0*v0z + s1*v1z + s2*v2z + s3*v3z;
                a2.w += s0*v0w + s1*v1w + s2*v2w + s3*v3w;
                az.x += z0*v0x + z1*v1x + z2*v2x + z3*v3x;
                az.y += z0*v0y + z1*v1y + z2*v2y + z3*v3y;
                az.z += z0*v0z + z1*v1z + z2*v2z + z3*v3z;
                az.w += z0*v0w + z1*v1w + z2*v2w + z3*v3w;
            }
            for (; p < p1; ++p) {
                int j = P.col_i[p];
                float w1 = P.s_do[j];
                float w2 = P.ce_i[p] * P.ci_s[j];
                float wz = P.co_s[j];
                ushort4 q = x4[(size_t)j * D4 + lane];
                float vx = bf2f(q.x), vy = bf2f(q.y), vz = bf2f(q.z), vw = bf2f(q.w);
                a1.x += w1 * vx; a1.y += w1 * vy; a1.z += w1 * vz; a1.w += w1 * vw;
                a2.x += w2 * vx; a2.y += w2 * vy; a2.z += w2 * vz; a2.w += w2 * vw;
                az.x += wz * vx; az.y += wz * vy; az.z += wz * vz; az.w += wz * vw;
            }
            float wd = P.d_i[wid] * P.ci_s[wid];
            ushort4 qi = x4[(size_t)wid * D4 + lane];
            a2.x += wd * bf2f(qi.x); a2.y += wd * bf2f(qi.y); a2.z += wd * bf2f(qi.z); a2.w += wd * bf2f(qi.w);
            float c1 = 0.35f * P.s_di[wid];
            float c2 = -0.15f * P.ri_s[wid];
            float4 r;
            r.x = c1 * a1.x + c2 * a2.x;
            r.y = c1 * a1.y + c2 * a2.y;
            r.z = c1 * a1.z + c2 * a2.z;
            r.w = c1 * a1.w + c2 * a2.w;
            ((float4*)P.Ydst)[(size_t)wid * D4 + lane] = r;
            ushort4 zq = { f2bf(az.x), f2bf(az.y), f2bf(az.z), f2bf(az.w) };
            ((ushort4*)P.zbuf)[(size_t)wid * D4 + lane] = zq;
        }
    }
    grid.sync();

    // ================= P5: pass B (csr_out) -> Ysrc full + z2 =================
    {
        const ushort4* x4 = (const ushort4*)P.xb;
        const ushort4* z4 = (const ushort4*)P.zbuf;
        for (int wid = gwave; wid < N_NODES; wid += 2048) {
            float4 a1 = {0,0,0,0}, a2 = {0,0,0,0}, az = {0,0,0,0}, a3 = {0,0,0,0};
            int p0 = wid << 7, p1 = p0 + P.ideg_o[wid];
            int p = p0;
            for (; p + 2 <= p1; p += 2) {
                int j0 = P.col_o[p], j1 = P.col_o[p+1];
                ushort4 q0 = x4[(size_t)j0 * D4 + lane];
                ushort4 q1 = x4[(size_t)j1 * D4 + lane];
                ushort4 u0 = z4[(size_t)j0 * D4 + lane];
                ushort4 u1 = z4[(size_t)j1 * D4 + lane];
                float f0 = P.s_di[j0], f1 = P.s_di[j1];
                float s0 = P.ce_o[p]   * P.co_s[j0];
                float s1 = P.ce_o[p+1] * P.co_s[j1];
                float w0 = P.ci_s[j0], w1 = P.ci_s[j1];
                float v0x = bf2f(q0.x), v0y = bf2f(q0.y), v0z = bf2f(q0.z), v0w = bf2f(q0.w);
                float v1x = bf2f(q1.x), v1y = bf2f(q1.y), v1z = bf2f(q1.z), v1w = bf2f(q1.w);
                a1.x += f0*v0x + f1*v1x;  a1.y += f0*v0y + f1*v1y;
                a1.z += f0*v0z + f1*v1z;  a1.w += f0*v0w + f1*v1w;
                a2.x += s0*v0x + s1*v1x;  a2.y += s0*v0y + s1*v1y;
                a2.z += s0*v0z + s1*v1z;  a2.w += s0*v0w + s1*v1w;
                az.x += w0*v0x + w1*v1x;  az.y += w0*v0y + w1*v1y;
                az.z += w0*v0z + w1*v1z;  az.w += w0*v0w + w1*v1w;
                a3.x += bf2f(u0.x) + bf2f(u1.x);  a3.y += bf2f(u0.y) + bf2f(u1.y);
                a3.z += bf2f(u0.z) + bf2f(u1.z);  a3.w += bf2f(u0.w) + bf2f(u1.w);
            }
            for (; p < p1; ++p) {
                int j = P.col_o[p];
                ushort4 q = x4[(size_t)j * D4 + lane];
                ushort4 u = z4[(size_t)j * D4 + lane];
                float w1 = P.s_di[j];
                float w2 = P.ce_o[p] * P.co_s[j];
                float wz = P.ci_s[j];
                float vx = bf2f(q.x), vy = bf2f(q.y), vz = bf2f(q.z), vw = bf2f(q.w);
                a1.x += w1 * vx; a1.y += w1 * vy; a1.z += w1 * vz; a1.w += w1 * vw;
                a2.x += w2 * vx; a2.y += w2 * vy; a2.z += w2 * vz; a2.w += w2 * vw;
                az.x += wz * vx; az.y += wz * vy; az.z += wz * vz; az.w += wz * vw;
                a3.x += bf2f(u.x); a3.y += bf2f(u.y); a3.z += bf2f(u.z); a3.w += bf2f(u.w);
            }
            float wd = P.d_o[wid] * P.co_s[wid];
            ushort4 qi = x4[(size_t)wid * D4 + lane];
            a2.x += wd * bf2f(qi.x); a2.y += wd * bf2f(qi.y); a2.z += wd * bf2f(qi.z); a2.w += wd * bf2f(qi.w);
            float c1 = 0.35f * P.s_do[wid];
            float c2 = 0.15f * P.ro_s[wid];
            float4 r;
            r.x = c1 * a1.x + c2 * (a3.x - a2.x);
            r.y = c1 * a1.y + c2 * (a3.y - a2.y);
            r.z = c1 * a1.z + c2 * (a3.z - a2.z);
            r.w = c1 * a1.w + c2 * (a3.w - a2.w);
            ((float4*)P.Ysrc)[(size_t)wid * D4 + lane] = r;
            ushort4 zq = { f2bf(az.x), f2bf(az.y), f2bf(az.z), f2bf(az.w) };
            ((ushort4*)P.z2buf)[(size_t)wid * D4 + lane] = zq;
        }
    }
    grid.sync();

    // ================= P6: pass C -> Ydst += 0.15*ri_s*(At@z2) =================
    {
        const ushort4* z4 = (const ushort4*)P.z2buf;
        for (int wid = gwave; wid < N_NODES; wid += 2048) {
            float4 a = {0,0,0,0};
            int p0 = wid << 7, p1 = p0 + P.ideg_i[wid];
            int p = p0;
            for (; p + 4 <= p1; p += 4) {
                int j0 = P.col_i[p], j1 = P.col_i[p+1], j2 = P.col_i[p+2], j3 = P.col_i[p+3];
                ushort4 v0 = z4[(size_t)j0 * D4 + lane];
                ushort4 v1 = z4[(size_t)j1 * D4 + lane];
                ushort4 v2 = z4[(size_t)j2 * D4 + lane];
                ushort4 v3 = z4[(size_t)j3 * D4 + lane];
                a.x += bf2f(v0.x) + bf2f(v1.x) + bf2f(v2.x) + bf2f(v3.x);
                a.y += bf2f(v0.y) + bf2f(v1.y) + bf2f(v2.y) + bf2f(v3.y);
                a.z += bf2f(v0.z) + bf2f(v1.z) + bf2f(v2.z) + bf2f(v3.z);
                a.w += bf2f(v0.w) + bf2f(v1.w) + bf2f(v2.w) + bf2f(v3.w);
            }
            for (; p < p1; ++p) {
                int j = P.col_i[p];
                ushort4 v = z4[(size_t)j * D4 + lane];
                a.x += bf2f(v.x); a.y += bf2f(v.y); a.z += bf2f(v.z); a.w += bf2f(v.w);
            }
            float s = 0.15f * P.ri_s[wid];
            float4* y4 = (float4*)P.Ydst;
            float4 cur = y4[(size_t)wid * D4 + lane];
            cur.x += s * a.x; cur.y += s * a.y; cur.z += s * a.z; cur.w += s * a.w;
            y4[(size_t)wid * D4 + lane] = cur;
        }
    }
    grid.sync();

    // ================= P7: out = Ysrc@Ws^T + Ydst@Wd^T + 0.5*(bs+bd) =================
    // 64x32 tiles, 512 tiles = 1/block. K-major LDS (As stride 68, Bs stride 36).
    {
        float* As = smem;              // [32][68]
        float* Bs = smem + 32 * 68;    // [32][36]
        int bid  = blockIdx.x;
        int row0 = (bid >> 3) * 64;
        int col0 = (bid & 7) * 32;
        int tx = tid & 7,  ty = tid >> 3;     // tx: 8 col-groups x4, ty: 32 row-groups x2
        int lr = tid >> 2;                    // A-load row 0..63
        int lc = (tid & 3) * 8;               // 8 k per thread
        int wr = tid >> 3;                    // B-load row (W row) 0..31
        int wk = (tid & 7) * 4;               // 4 k per thread
        float acc[2][4] = {};
        for (int half = 0; half < 2; ++half) {
            const float* Y = half ? P.Ydst : P.Ysrc;
            const float* W = half ? P.Wd : P.Ws;
            for (int k0 = 0; k0 < 256; k0 += 32) {
                float4 a0 = *(const float4*)&Y[(size_t)(row0 + lr) * 256 + k0 + lc];
                float4 a1 = *(const float4*)&Y[(size_t)(row0 + lr) * 256 + k0 + lc + 4];
                float4 b0 = *(const float4*)&W[(size_t)(col0 + wr) * 256 + k0 + wk];
                __syncthreads();
                As[(lc+0)*68 + lr] = a0.x; As[(lc+1)*68 + lr] = a0.y;
                As[(lc+2)*68 + lr] = a0.z; As[(lc+3)*68 + lr] = a0.w;
                As[(lc+4)*68 + lr] = a1.x; As[(lc+5)*68 + lr] = a1.y;
                As[(lc+6)*68 + lr] = a1.z; As[(lc+7)*68 + lr] = a1.w;
                Bs[(wk+0)*36 + wr] = b0.x; Bs[(wk+1)*36 + wr] = b0.y;
                Bs[(wk+2)*36 + wr] = b0.z; Bs[(wk+3)*36 + wr] = b0.w;
                __syncthreads();
#pragma unroll
                for (int kk = 0; kk < 32; ++kk) {
                    float2 av = *(const float2*)&As[kk * 68 + ty * 2];
                    float4 bv = *(const float4*)&Bs[kk * 36 + tx * 4];
                    acc[0][0] += av.x * bv.x; acc[0][1] += av.x * bv.y;
                    acc[0][2] += av.x * bv.z; acc[0][3] += av.x * bv.w;
                    acc[1][0] += av.y * bv.x; acc[1][1] += av.y * bv.y;
                    acc[1][2] += av.y * bv.z; acc[1][3] += av.y * bv.w;
                }
            }
        }
#pragma unroll
        for (int r = 0; r < 2; ++r) {
            int orow = row0 + ty * 2 + r;
            int ocol = col0 + tx * 4;
            float4 v;
            v.x = acc[r][0] + 0.5f * (P.bs[ocol+0] + P.bd[ocol+0]);
            v.y = acc[r][1] + 0.5f * (P.bs[ocol+1] + P.bd[ocol+1]);
            v.z = acc[r][2] + 0.5f * (P.bs[ocol+2] + P.bd[ocol+2]);
            v.w = acc[r][3] + 0.5f * (P.bs[ocol+3] + P.bd[ocol+3]);
            *(float4*)&P.out[(size_t)orow * 256 + ocol] = v;
        }
    }
}

// ---------------------------------------------------------------- launch
extern "C" void kernel_launch(void* const* d_in, const int* in_sizes, int n_in,
                              void* d_out, int out_size, void* d_ws, size_t ws_size,
                              hipStream_t stream) {
    char* ws = (char*)d_ws;
    size_t off = 0;
    auto alloc = [&](size_t bytes) -> void* {
        void* p = ws + off;
        off = (off + bytes + 255) & ~(size_t)255;
        return p;
    };
    Params P;
    P.x   = (const float*)d_in[0];
    P.ei  = (const int*)  d_in[1];
    P.Ws  = (const float*)d_in[2];
    P.bs  = (const float*)d_in[3];
    P.Wd  = (const float*)d_in[4];
    P.bd  = (const float*)d_in[5];
    P.out = (float*)d_out;
    // Ab|Atb|csub_o|csub_i contiguous (each size multiple of 256 B) -> zeroed in P0.
    P.Ab     = (u64*)  alloc((size_t)N_NODES * NWORDS * 8);   // 2 MB
    P.Atb    = (u64*)  alloc((size_t)N_NODES * NWORDS * 8);   // 2 MB
    P.csub_o = (float*)alloc(N_NODES * 4);
    P.csub_i = (float*)alloc(N_NODES * 4);
    P.xb     = (unsigned short*)alloc((size_t)N_NODES * D_FEAT * 2);   // 2 MB bf16
    P.d_o    = (float*)alloc(N_NODES * 4);
    P.d_i    = (float*)alloc(N_NODES * 4);
    P.ideg_o = (int*)  alloc(N_NODES * 4);
    P.ideg_i = (int*)  alloc(N_NODES * 4);
    P.col_o  = (int*)  alloc((size_t)N_NODES * ELL * 4);      // 2 MB
    P.col_i  = (int*)  alloc((size_t)N_NODES * ELL * 4);      // 2 MB
    P.ce_o   = (float*)alloc((size_t)N_NODES * ELL * 4);      // 2 MB
    P.ce_i   = (float*)alloc((size_t)N_NODES * ELL * 4);      // 2 MB
    P.rsub_o = (float*)alloc(N_NODES * 4);
    P.rsub_i = (float*)alloc(N_NODES * 4);
    P.s_do   = (float*)alloc(N_NODES * 4);
    P.s_di   = (float*)alloc(N_NODES * 4);
    P.ro_s   = (float*)alloc(N_NODES * 4);
    P.co_s   = (float*)alloc(N_NODES * 4);
    P.ri_s   = (float*)alloc(N_NODES * 4);
    P.ci_s   = (float*)alloc(N_NODES * 4);
    P.zbuf   = (unsigned short*)alloc((size_t)N_NODES * D_FEAT * 2);  // 2 MB bf16
    P.z2buf  = (unsigned short*)alloc((size_t)N_NODES * D_FEAT * 2);  // 2 MB bf16
    P.Ysrc   = (float*)alloc((size_t)N_NODES * D_FEAT * 4);   // 4 MB
    P.Ydst   = (float*)alloc((size_t)N_NODES * D_FEAT * 4);   // 4 MB

    void* args[] = { &P };
    hipLaunchCooperativeKernel((void*)k_all, dim3(NBLK), dim3(NTHR), args, 0, stream);
}

// Round 12
// 174.663 us; speedup vs baseline: 3.4894x; 3.4894x over previous
//
#include <hip/hip_runtime.h>
#include <cstdint>
#include <cstddef>

#define N_NODES 4096
#define NWORDS  64          // 4096 bits / 64
#define E_EDGES 131072
#define D_FEAT  256
#define D4      (D_FEAT/4)  // 64 ushort4 groups per row (4 feats per lane)
#define ELL     128         // fixed slots per node (Poisson(32) -> P(deg>128) ~ 1e-40)

typedef unsigned long long u64;

__device__ inline float bf2f(unsigned short u) {
    return __uint_as_float(((unsigned int)u) << 16);
}
__device__ inline unsigned short f2bf(float f) {   // round-to-nearest-even
    unsigned int u = __float_as_uint(f);
    return (unsigned short)((u + 0x7fffu + ((u >> 16) & 1u)) >> 16);
}

// ---------------------------------------------------------------- scatter + x->bf16 convert (disjoint block ranges)
__global__ __launch_bounds__(256) void k_scatter_cvt(const int* __restrict__ ei,
                                                     u64* __restrict__ Ab, u64* __restrict__ Atb,
                                                     const float* __restrict__ x, unsigned short* __restrict__ xb) {
    int b = blockIdx.x;
    if (b < E_EDGES / 256) {
        int e = b * 256 + threadIdx.x;
        int r = ei[e];
        int c = ei[E_EDGES + e];
        atomicOr(&Ab [(size_t)r * NWORDS + (c >> 6)], 1ull << (c & 63));
        atomicOr(&Atb[(size_t)c * NWORDS + (r >> 6)], 1ull << (r & 63));
    } else {
        int i = (b - E_EDGES / 256) * 256 + threadIdx.x;   // over N*D/4 groups
        float4 v = ((const float4*)x)[i];
        ushort4 q = { f2bf(v.x), f2bf(v.y), f2bf(v.z), f2bf(v.w) };
        ((ushort4*)xb)[i] = q;
    }
}

// ---------------------------------------------------------------- fill + degree + per-edge intersections (wave per node-dir)
__global__ __launch_bounds__(256) void k_fill_so(const u64* __restrict__ Ab,  int* __restrict__ col_o,
                                                 float* __restrict__ d_o, int* __restrict__ ideg_o,
                                                 float* __restrict__ ce_o, float* __restrict__ rsub_o, float* __restrict__ csub_o,
                                                 const u64* __restrict__ Atb, int* __restrict__ col_i,
                                                 float* __restrict__ d_i, int* __restrict__ ideg_i,
                                                 float* __restrict__ ce_i, float* __restrict__ rsub_i, float* __restrict__ csub_i) {
    __shared__ int lcol[4][ELL];
    int wslot = threadIdx.x >> 6;
    int gw   = (blockIdx.x * blockDim.x + threadIdx.x) >> 6;
    int lane = threadIdx.x & 63;
    if (gw >= 2 * N_NODES) return;
    int half = gw >= N_NODES;
    int wid  = half ? gw - N_NODES : gw;
    const u64* bits = half ? Atb : Ab;
    int*       cols = half ? col_i : col_o;
    float*     dd   = half ? d_i   : d_o;
    int*       idg  = half ? ideg_i : ideg_o;
    float*     ce   = half ? ce_i   : ce_o;
    float*     rsub = half ? rsub_i : rsub_o;
    float*     csub = half ? csub_i : csub_o;

    // --- extract list ---
    u64 wv = bits[(size_t)wid * NWORDS + lane];
    int cnt = __popcll(wv);
    int inc = cnt;
    for (int off = 1; off < 64; off <<= 1) {
        int t = __shfl_up(inc, off);
        if (lane >= off) inc += t;
    }
    int deg = __shfl(inc, 63);
    int pos = inc - cnt;                    // exclusive prefix within node
    u64 t = wv;
    int base = wid << 7;
    while (t) {
        int b = __builtin_ctzll(t);
        int c = lane * 64 + b;
        lcol[wslot][pos] = c;
        cols[base + pos] = c;
        ++pos;
        t &= t - 1;
    }
    if (lane == 63) { dd[wid] = (float)deg; idg[wid] = deg; }

    // --- intersections over own list (LDS) ---
    int g = lane >> 4, s = lane & 15;
    const u64* aw = &bits[(size_t)wid * NWORDS + s * 4];
    u64 a0 = aw[0], a1 = aw[1], a2 = aw[2], a3 = aw[3];
    float rs = 0.f;
    for (int p = g; p < deg; p += 4) {
        int j = lcol[wslot][p];
        const u64* bw = &bits[(size_t)j * NWORDS + s * 4];
        u64 b0 = bw[0], b1 = bw[1], b2 = bw[2], b3 = bw[3];
        int c = __popcll(a0 & b0) + __popcll(a1 & b1) + __popcll(a2 & b2) + __popcll(a3 & b3);
        c += __shfl_xor(c, 1);
        c += __shfl_xor(c, 2);
        c += __shfl_xor(c, 4);
        c += __shfl_xor(c, 8);
        if (s == 0) {
            float cf = (j == wid) ? 0.f : (float)c;   // self-loop handled by diag term
            ce[base + p] = cf;
            if (cf != 0.f) atomicAdd(&csub[j], cf);
            rs += cf;
        }
    }
    rs += __shfl_xor(rs, 16); rs += __shfl_xor(rs, 32);
    if (lane == 0) rsub[wid] = rs;
}

// ---------------------------------------------------------------- rfull gather + scales (wave per node-dir)
__global__ __launch_bounds__(256) void k_finalize2(const int* __restrict__ ideg_o, const int* __restrict__ col_o,
                                                   const float* __restrict__ d_o,
                                                   const int* __restrict__ ideg_i, const int* __restrict__ col_i,
                                                   const float* __restrict__ d_i,
                                                   const float* __restrict__ rsub_o, const float* __restrict__ csub_o,
                                                   const float* __restrict__ rsub_i, const float* __restrict__ csub_i,
                                                   float* __restrict__ s_do, float* __restrict__ s_di,
                                                   float* __restrict__ ro_s, float* __restrict__ co_s,
                                                   float* __restrict__ ri_s, float* __restrict__ ci_s) {
    int gw   = (blockIdx.x * blockDim.x + threadIdx.x) >> 6;
    int lane = threadIdx.x & 63;
    if (gw >= 2 * N_NODES) return;
    int half = gw >= N_NODES;
    int wid  = half ? gw - N_NODES : gw;
    const int*   cols = half ? col_i  : col_o;
    const int*   idg  = half ? ideg_i : ideg_o;
    const float* dcol = half ? d_o    : d_i;     // neighbor degree in the OTHER direction
    int deg = idg[wid];
    int base = wid << 7;
    float rf = 0.f;
    for (int l = lane; l < deg; l += 64) rf += dcol[cols[base + l]];
    for (int off = 32; off; off >>= 1) rf += __shfl_xor(rf, off);
    if (lane == 0) {
        float dself = (half ? d_i : d_o)[wid];
        float sd = dself > 0.f ? rsqrtf(dself) : 0.f;
        (half ? s_di : s_do)[wid] = sd;
        float rsv = (half ? rsub_i : rsub_o)[wid];
        float csv = (half ? csub_i : csub_o)[wid];
        float r_ = rf - dself - rsv;     // masked SO row sum
        float c_ = rf - dself - csv;     // masked SO col sum
        (half ? ri_s : ro_s)[wid] = r_ > 0.f ? rsqrtf(r_) : 0.f;
        (half ? ci_s : co_s)[wid] = c_ > 0.f ? rsqrtf(c_) : 0.f;
    }
}

// ---------------------------------------------------------------- pass A (csr_in): Ydst partial + z — 2 waves per node
__global__ __launch_bounds__(256) void k_fused_pass(const int* __restrict__ idg, const int* __restrict__ cols,
                                                    const float* __restrict__ ce, const unsigned short* __restrict__ xb,
                                                    float* __restrict__ Y, unsigned short* __restrict__ zout,
                                                    const float* __restrict__ srow_fo, const float* __restrict__ scol_fo,
                                                    const float* __restrict__ srow_so, const float* __restrict__ scol_so,
                                                    const float* __restrict__ scol_z, const float* __restrict__ dself) {
    __shared__ float4 red[2][3][64];
    int gw   = (blockIdx.x * blockDim.x + threadIdx.x) >> 6;   // 0..8191
    int lane = threadIdx.x & 63;
    int pairslot = (threadIdx.x >> 6) >> 1;                    // 0..1
    int sub = gw & 1;
    int wid = gw >> 1;
    const ushort4* x4 = (const ushort4*)xb;
    float4 a1 = {0,0,0,0}, a2 = {0,0,0,0}, az = {0,0,0,0};
    int p0 = wid << 7, p1 = p0 + idg[wid];
    for (int p = p0 + sub * 4; p < p1; p += 8) {
        if (p + 4 <= p1) {
            int j0 = cols[p], j1 = cols[p+1], j2 = cols[p+2], j3 = cols[p+3];
            ushort4 q0 = x4[(size_t)j0 * D4 + lane];
            ushort4 q1 = x4[(size_t)j1 * D4 + lane];
            ushort4 q2 = x4[(size_t)j2 * D4 + lane];
            ushort4 q3 = x4[(size_t)j3 * D4 + lane];
            float f0 = scol_fo[j0], f1 = scol_fo[j1], f2 = scol_fo[j2], f3 = scol_fo[j3];
            float s0 = ce[p]   * scol_so[j0];
            float s1 = ce[p+1] * scol_so[j1];
            float s2 = ce[p+2] * scol_so[j2];
            float s3 = ce[p+3] * scol_so[j3];
            float z0 = scol_z[j0], z1 = scol_z[j1], z2 = scol_z[j2], z3 = scol_z[j3];
            float v0x = bf2f(q0.x), v0y = bf2f(q0.y), v0z = bf2f(q0.z), v0w = bf2f(q0.w);
            float v1x = bf2f(q1.x), v1y = bf2f(q1.y), v1z = bf2f(q1.z), v1w = bf2f(q1.w);
            float v2x = bf2f(q2.x), v2y = bf2f(q2.y), v2z = bf2f(q2.z), v2w = bf2f(q2.w);
            float v3x = bf2f(q3.x), v3y = bf2f(q3.y), v3z = bf2f(q3.z), v3w = bf2f(q3.w);
            a1.x += f0*v0x + f1*v1x + f2*v2x + f3*v3x;
            a1.y += f0*v0y + f1*v1y + f2*v2y + f3*v3y;
            a1.z += f0*v0z + f1*v1z + f2*v2z + f3*v3z;
            a1.w += f0*v0w + f1*v1w + f2*v2w + f3*v3w;
            a2.x += s0*v0x + s1*v1x + s2*v2x + s3*v3x;
            a2.y += s0*v0y + s1*v1y + s2*v2y + s3*v3y;
            a2.z += s0*v0z + s1*v1z + s2*v2z + s3*v3z;
            a2.w += s0*v0w + s1*v1w + s2*v2w + s3*v3w;
            az.x += z0*v0x + z1*v1x + z2*v2x + z3*v3x;
            az.y += z0*v0y + z1*v1y + z2*v2y + z3*v3y;
            az.z += z0*v0z + z1*v1z + z2*v2z + z3*v3z;
            az.w += z0*v0w + z1*v1w + z2*v2w + z3*v3w;
        } else {
            for (int q = p; q < p1; ++q) {
                int j = cols[q];
                float w1 = scol_fo[j];
                float w2 = ce[q] * scol_so[j];
                float wz = scol_z[j];
                ushort4 qq = x4[(size_t)j * D4 + lane];
                float vx = bf2f(qq.x), vy = bf2f(qq.y), vz = bf2f(qq.z), vw = bf2f(qq.w);
                a1.x += w1 * vx; a1.y += w1 * vy; a1.z += w1 * vz; a1.w += w1 * vw;
                a2.x += w2 * vx; a2.y += w2 * vy; a2.z += w2 * vz; a2.w += w2 * vw;
                az.x += wz * vx; az.y += wz * vy; az.z += wz * vz; az.w += wz * vw;
            }
        }
    }
    if (sub == 1) {
        red[pairslot][0][lane] = a1;
        red[pairslot][1][lane] = a2;
        red[pairslot][2][lane] = az;
    }
    __syncthreads();
    if (sub == 0) {
        float4 b1 = red[pairslot][0][lane], b2 = red[pairslot][1][lane], bz = red[pairslot][2][lane];
        a1.x += b1.x; a1.y += b1.y; a1.z += b1.z; a1.w += b1.w;
        a2.x += b2.x; a2.y += b2.y; a2.z += b2.z; a2.w += b2.w;
        az.x += bz.x; az.y += bz.y; az.z += bz.z; az.w += bz.w;
        float wd = dself[wid] * scol_so[wid];
        ushort4 qi = x4[(size_t)wid * D4 + lane];
        a2.x += wd * bf2f(qi.x); a2.y += wd * bf2f(qi.y); a2.z += wd * bf2f(qi.z); a2.w += wd * bf2f(qi.w);
        float c1 = 0.35f * srow_fo[wid];
        float c2 = -0.15f * srow_so[wid];
        float4 r;
        r.x = c1 * a1.x + c2 * a2.x;
        r.y = c1 * a1.y + c2 * a2.y;
        r.z = c1 * a1.z + c2 * a2.z;
        r.w = c1 * a1.w + c2 * a2.w;
        ((float4*)Y)[(size_t)wid * D4 + lane] = r;
        ushort4 zq = { f2bf(az.x), f2bf(az.y), f2bf(az.z), f2bf(az.w) };
        ((ushort4*)zout)[(size_t)wid * D4 + lane] = zq;
    }
}

// ---------------------------------------------------------------- pass B (csr_out, fused): full Ysrc + z2 — 2 waves per node
__global__ __launch_bounds__(256) void k_pass_b(const int* __restrict__ idg, const int* __restrict__ cols,
                                                const float* __restrict__ ce, const unsigned short* __restrict__ xb,
                                                const unsigned short* __restrict__ zin,
                                                float* __restrict__ Y, unsigned short* __restrict__ z2out,
                                                const float* __restrict__ s_do, const float* __restrict__ s_di,
                                                const float* __restrict__ ro_s, const float* __restrict__ co_s,
                                                const float* __restrict__ ci_s, const float* __restrict__ d_o) {
    __shared__ float4 red[2][4][64];
    int gw   = (blockIdx.x * blockDim.x + threadIdx.x) >> 6;
    int lane = threadIdx.x & 63;
    int pairslot = (threadIdx.x >> 6) >> 1;
    int sub = gw & 1;
    int wid = gw >> 1;
    const ushort4* x4 = (const ushort4*)xb;
    const ushort4* z4 = (const ushort4*)zin;
    float4 a1 = {0,0,0,0}, a2 = {0,0,0,0}, az = {0,0,0,0}, a3 = {0,0,0,0};
    int p0 = wid << 7, p1 = p0 + idg[wid];
    for (int p = p0 + sub * 2; p < p1; p += 4) {
        if (p + 2 <= p1) {
            int j0 = cols[p], j1 = cols[p+1];
            ushort4 q0 = x4[(size_t)j0 * D4 + lane];
            ushort4 q1 = x4[(size_t)j1 * D4 + lane];
            ushort4 u0 = z4[(size_t)j0 * D4 + lane];
            ushort4 u1 = z4[(size_t)j1 * D4 + lane];
            float f0 = s_di[j0], f1 = s_di[j1];
            float s0 = ce[p]   * co_s[j0];
            float s1 = ce[p+1] * co_s[j1];
            float w0 = ci_s[j0], w1 = ci_s[j1];
            float v0x = bf2f(q0.x), v0y = bf2f(q0.y), v0z = bf2f(q0.z), v0w = bf2f(q0.w);
            float v1x = bf2f(q1.x), v1y = bf2f(q1.y), v1z = bf2f(q1.z), v1w = bf2f(q1.w);
            a1.x += f0*v0x + f1*v1x;  a1.y += f0*v0y + f1*v1y;
            a1.z += f0*v0z + f1*v1z;  a1.w += f0*v0w + f1*v1w;
            a2.x += s0*v0x + s1*v1x;  a2.y += s0*v0y + s1*v1y;
            a2.z += s0*v0z + s1*v1z;  a2.w += s0*v0w + s1*v1w;
            az.x += w0*v0x + w1*v1x;  az.y += w0*v0y + w1*v1y;
            az.z += w0*v0z + w1*v1z;  az.w += w0*v0w + w1*v1w;
            a3.x += bf2f(u0.x) + bf2f(u1.x);  a3.y += bf2f(u0.y) + bf2f(u1.y);
            a3.z += bf2f(u0.z) + bf2f(u1.z);  a3.w += bf2f(u0.w) + bf2f(u1.w);
        } else {
            int j = cols[p];
            ushort4 q = x4[(size_t)j * D4 + lane];
            ushort4 u = z4[(size_t)j * D4 + lane];
            float w1 = s_di[j];
            float w2 = ce[p] * co_s[j];
            float wz = ci_s[j];
            float vx = bf2f(q.x), vy = bf2f(q.y), vz = bf2f(q.z), vw = bf2f(q.w);
            a1.x += w1 * vx; a1.y += w1 * vy; a1.z += w1 * vz; a1.w += w1 * vw;
            a2.x += w2 * vx; a2.y += w2 * vy; a2.z += w2 * vz; a2.w += w2 * vw;
            az.x += wz * vx; az.y += wz * vy; az.z += wz * vz; az.w += wz * vw;
            a3.x += bf2f(u.x); a3.y += bf2f(u.y); a3.z += bf2f(u.z); a3.w += bf2f(u.w);
        }
    }
    if (sub == 1) {
        red[pairslot][0][lane] = a1;
        red[pairslot][1][lane] = a2;
        red[pairslot][2][lane] = az;
        red[pairslot][3][lane] = a3;
    }
    __syncthreads();
    if (sub == 0) {
        float4 b1 = red[pairslot][0][lane], b2 = red[pairslot][1][lane];
        float4 bz = red[pairslot][2][lane], b3 = red[pairslot][3][lane];
        a1.x += b1.x; a1.y += b1.y; a1.z += b1.z; a1.w += b1.w;
        a2.x += b2.x; a2.y += b2.y; a2.z += b2.z; a2.w += b2.w;
        az.x += bz.x; az.y += bz.y; az.z += bz.z; az.w += bz.w;
        a3.x += b3.x; a3.y += b3.y; a3.z += b3.z; a3.w += b3.w;
        float wd = d_o[wid] * co_s[wid];
        ushort4 qi = x4[(size_t)wid * D4 + lane];
        a2.x += wd * bf2f(qi.x); a2.y += wd * bf2f(qi.y); a2.z += wd * bf2f(qi.z); a2.w += wd * bf2f(qi.w);
        float c1 = 0.35f * s_do[wid];
        float c2 = 0.15f * ro_s[wid];
        float4 r;
        r.x = c1 * a1.x + c2 * (a3.x - a2.x);
        r.y = c1 * a1.y + c2 * (a3.y - a2.y);
        r.z = c1 * a1.z + c2 * (a3.z - a2.z);
        r.w = c1 * a1.w + c2 * (a3.w - a2.w);
        ((float4*)Y)[(size_t)wid * D4 + lane] = r;
        ushort4 zq = { f2bf(az.x), f2bf(az.y), f2bf(az.z), f2bf(az.w) };
        ((ushort4*)z2out)[(size_t)wid * D4 + lane] = zq;
    }
}

// ---------------------------------------------------------------- pass C: Y[i] += 0.15*srow[i]*Sum_j z2[j] — 2 waves per node
__global__ __launch_bounds__(256) void k_spmm_accum(const int* __restrict__ idg, const int* __restrict__ cols,
                                                    const unsigned short* __restrict__ zin, float* __restrict__ Y,
                                                    const float* __restrict__ srow) {
    __shared__ float4 red[2][64];
    int gw   = (blockIdx.x * blockDim.x + threadIdx.x) >> 6;
    int lane = threadIdx.x & 63;
    int pairslot = (threadIdx.x >> 6) >> 1;
    int sub = gw & 1;
    int wid = gw >> 1;
    const ushort4* z4 = (const ushort4*)zin;
    float4 a = {0,0,0,0};
    int p0 = wid << 7, p1 = p0 + idg[wid];
    for (int p = p0 + sub * 4; p < p1; p += 8) {
        if (p + 4 <= p1) {
            int j0 = cols[p], j1 = cols[p+1], j2 = cols[p+2], j3 = cols[p+3];
            ushort4 v0 = z4[(size_t)j0 * D4 + lane];
            ushort4 v1 = z4[(size_t)j1 * D4 + lane];
            ushort4 v2 = z4[(size_t)j2 * D4 + lane];
            ushort4 v3 = z4[(size_t)j3 * D4 + lane];
            a.x += bf2f(v0.x) + bf2f(v1.x) + bf2f(v2.x) + bf2f(v3.x);
            a.y += bf2f(v0.y) + bf2f(v1.y) + bf2f(v2.y) + bf2f(v3.y);
            a.z += bf2f(v0.z) + bf2f(v1.z) + bf2f(v2.z) + bf2f(v3.z);
            a.w += bf2f(v0.w) + bf2f(v1.w) + bf2f(v2.w) + bf2f(v3.w);
        } else {
            for (int q = p; q < p1; ++q) {
                int j = cols[q];
                ushort4 v = z4[(size_t)j * D4 + lane];
                a.x += bf2f(v.x); a.y += bf2f(v.y); a.z += bf2f(v.z); a.w += bf2f(v.w);
            }
        }
    }
    if (sub == 1) red[pairslot][lane] = a;
    __syncthreads();
    if (sub == 0) {
        float4 b = red[pairslot][lane];
        a.x += b.x; a.y += b.y; a.z += b.z; a.w += b.w;
        float s = 0.15f * srow[wid];
        float4* y4 = (float4*)Y;
        float4 cur = y4[(size_t)wid * D4 + lane];
        cur.x += s * a.x; cur.y += s * a.y; cur.z += s * a.z; cur.w += s * a.w;
        y4[(size_t)wid * D4 + lane] = cur;
    }
}

// ---------------------------------------------------------------- final GEMM, both halves, 64x32 tiles (512 blocks):
// out = Ysrc@Ws^T + Ydst@Wd^T + 0.5*(bs+bd)
__global__ __launch_bounds__(256) void k_sgemm_both(const float* __restrict__ Ysrc, const float* __restrict__ Ydst,
                                                    const float* __restrict__ Ws, const float* __restrict__ Wd,
                                                    const float* __restrict__ bsrc, const float* __restrict__ bdst,
                                                    float* __restrict__ out) {
    __shared__ float As[32 * 68];
    __shared__ float Bs[32 * 36];
    int tid = threadIdx.x;
    int row0 = blockIdx.x * 64;
    int col0 = blockIdx.y * 32;
    int tx = tid & 7,  ty = tid >> 3;     // tx: 8 col-groups x4, ty: 32 row-groups x2
    int lr = tid >> 2;                    // A-load row 0..63
    int lc = (tid & 3) * 8;               // 8 k per thread
    int wr = tid >> 3;                    // B-load row (W row) 0..31
    int wk = (tid & 7) * 4;               // 4 k per thread
    float acc[2][4] = {};
    for (int half = 0; half < 2; ++half) {
        const float* Y = half ? Ydst : Ysrc;
        const float* W = half ? Wd : Ws;
        for (int k0 = 0; k0 < 256; k0 += 32) {
            float4 a0 = *(const float4*)&Y[(size_t)(row0 + lr) * 256 + k0 + lc];
            float4 a1 = *(const float4*)&Y[(size_t)(row0 + lr) * 256 + k0 + lc + 4];
            float4 b0 = *(const float4*)&W[(size_t)(col0 + wr) * 256 + k0 + wk];
            __syncthreads();
            As[(lc+0)*68 + lr] = a0.x; As[(lc+1)*68 + lr] = a0.y;
            As[(lc+2)*68 + lr] = a0.z; As[(lc+3)*68 + lr] = a0.w;
            As[(lc+4)*68 + lr] = a1.x; As[(lc+5)*68 + lr] = a1.y;
            As[(lc+6)*68 + lr] = a1.z; As[(lc+7)*68 + lr] = a1.w;
            Bs[(wk+0)*36 + wr] = b0.x; Bs[(wk+1)*36 + wr] = b0.y;
            Bs[(wk+2)*36 + wr] = b0.z; Bs[(wk+3)*36 + wr] = b0.w;
            __syncthreads();
#pragma unroll
            for (int kk = 0; kk < 32; ++kk) {
                float2 av = *(const float2*)&As[kk * 68 + ty * 2];
                float4 bv = *(const float4*)&Bs[kk * 36 + tx * 4];
                acc[0][0] += av.x * bv.x; acc[0][1] += av.x * bv.y;
                acc[0][2] += av.x * bv.z; acc[0][3] += av.x * bv.w;
                acc[1][0] += av.y * bv.x; acc[1][1] += av.y * bv.y;
                acc[1][2] += av.y * bv.z; acc[1][3] += av.y * bv.w;
            }
        }
    }
#pragma unroll
    for (int r = 0; r < 2; ++r) {
        int orow = row0 + ty * 2 + r;
        int ocol = col0 + tx * 4;
        float4 v;
        v.x = acc[r][0] + 0.5f * (bsrc[ocol+0] + bdst[ocol+0]);
        v.y = acc[r][1] + 0.5f * (bsrc[ocol+1] + bdst[ocol+1]);
        v.z = acc[r][2] + 0.5f * (bsrc[ocol+2] + bdst[ocol+2]);
        v.w = acc[r][3] + 0.5f * (bsrc[ocol+3] + bdst[ocol+3]);
        *(float4*)&out[(size_t)orow * 256 + ocol] = v;
    }
}

// ---------------------------------------------------------------- launch
extern "C" void kernel_launch(void* const* d_in, const int* in_sizes, int n_in,
                              void* d_out, int out_size, void* d_ws, size_t ws_size,
                              hipStream_t stream) {
    const float* x  = (const float*)d_in[0];
    const int*   ei = (const int*)  d_in[1];
    const float* Ws = (const float*)d_in[2];
    const float* bs = (const float*)d_in[3];
    const float* Wd = (const float*)d_in[4];
    const float* bd = (const float*)d_in[5];
    float* out = (float*)d_out;

    char* ws = (char*)d_ws;
    size_t off = 0;
    auto alloc = [&](size_t bytes) -> void* {
        void* p = ws + off;
        off = (off + bytes + 255) & ~(size_t)255;
        return p;
    };
    // Keep Ab|Atb|csub_o|csub_i contiguous: zeroed by ONE memset.
    u64*   Ab      = (u64*)  alloc((size_t)N_NODES * NWORDS * 8);   // 2 MB
    u64*   Atb     = (u64*)  alloc((size_t)N_NODES * NWORDS * 8);   // 2 MB
    float* csub_o  = (float*)alloc(N_NODES * 4);
    float* csub_i  = (float*)alloc(N_NODES * 4);
    unsigned short* xb = (unsigned short*)alloc((size_t)N_NODES * D_FEAT * 2);   // 2 MB bf16
    float* d_o     = (float*)alloc(N_NODES * 4);
    float* d_i     = (float*)alloc(N_NODES * 4);
    int*   ideg_o  = (int*)  alloc(N_NODES * 4);
    int*   ideg_i  = (int*)  alloc(N_NODES * 4);
    int*   col_o   = (int*)  alloc((size_t)N_NODES * ELL * 4);      // 2 MB
    int*   col_i   = (int*)  alloc((size_t)N_NODES * ELL * 4);      // 2 MB
    float* ce_o    = (float*)alloc((size_t)N_NODES * ELL * 4);      // 2 MB
    float* ce_i    = (float*)alloc((size_t)N_NODES * ELL * 4);      // 2 MB
    float* rsub_o  = (float*)alloc(N_NODES * 4);
    float* rsub_i  = (float*)alloc(N_NODES * 4);
    float* s_do    = (float*)alloc(N_NODES * 4);
    float* s_di    = (float*)alloc(N_NODES * 4);
    float* ro_s    = (float*)alloc(N_NODES * 4);
    float* co_s    = (float*)alloc(N_NODES * 4);
    float* ri_s    = (float*)alloc(N_NODES * 4);
    float* ci_s    = (float*)alloc(N_NODES * 4);
    unsigned short* zbuf  = (unsigned short*)alloc((size_t)N_NODES * D_FEAT * 2);  // 2 MB bf16
    unsigned short* z2buf = (unsigned short*)alloc((size_t)N_NODES * D_FEAT * 2);  // 2 MB bf16
    float* Ysrc    = (float*)alloc((size_t)N_NODES * D_FEAT * 4);   // 4 MB
    float* Ydst    = (float*)alloc((size_t)N_NODES * D_FEAT * 4);   // 4 MB

    // single zero-fill: Ab + Atb + csub_o + csub_i (contiguous)
    hipMemsetAsync(Ab, 0, (size_t)N_NODES * NWORDS * 8 * 2 + (size_t)N_NODES * 4 * 2, stream);

    // scatter (512 blocks) + x->bf16 convert (1024 blocks)
    k_scatter_cvt<<<E_EDGES / 256 + (N_NODES * D_FEAT / 4) / 256, 256, 0, stream>>>(ei, Ab, Atb, x, xb);
    // fill + degree + intersections (both directions)
    k_fill_so<<<(2 * N_NODES * 64) / 256, 256, 0, stream>>>(Ab,  col_o, d_o, ideg_o, ce_o, rsub_o, csub_o,
                                                            Atb, col_i, d_i, ideg_i, ce_i, rsub_i, csub_i);
    // rfull gather + scales
    k_finalize2<<<(2 * N_NODES * 64) / 256, 256, 0, stream>>>(ideg_o, col_o, d_o, ideg_i, col_i, d_i,
                                                              rsub_o, csub_o, rsub_i, csub_i,
                                                              s_do, s_di, ro_s, co_s, ri_s, ci_s);
    // Pass A (csr_in, 2 waves/node): Ydst = 0.35*At_n@x - 0.15*mask-corr(SO_in);  z = At@(co_s*x)
    k_fused_pass<<<(N_NODES * 2 * 64) / 256, 256, 0, stream>>>(ideg_i, col_i, ce_i, xb, Ydst, zbuf,
                                                               s_di, s_do, ri_s, ci_s, co_s, d_i);
    // Pass B (csr_out, 2 waves/node): Ysrc = 0.35*A_n@x + 0.15*ro_s*(A@z - corr);  z2 = A@(ci_s*x)
    k_pass_b<<<(N_NODES * 2 * 64) / 256, 256, 0, stream>>>(ideg_o, col_o, ce_o, xb, zbuf, Ysrc, z2buf,
                                                           s_do, s_di, ro_s, co_s, ci_s, d_o);
    // Pass C (2 waves/node): Ydst += 0.15*ri_s*(At@z2)
    k_spmm_accum<<<(N_NODES * 2 * 64) / 256, 256, 0, stream>>>(ideg_i, col_i, z2buf, Ydst, ri_s);
    // Final GEMM (both halves, 64x32 tiles) + bias, direct to out
    k_sgemm_both<<<dim3(N_NODES / 64, D_FEAT / 32), 256, 0, stream>>>(Ysrc, Ydst, Ws, Wd, bs, bd, out);
}